// Round 16
// baseline (220.451 us; speedup 1.0000x reference)
//
#include <hip/hip_runtime.h>
#include <math.h>

#define NATOMS 10000
#define NEDGES 320000
#define NBINS  (NATOMS * 4)   // bin = atom*4 + species; bin a*4+3 always empty
#define RC_F 5.0f
#define PI_F 3.14159265358979323846f

// ---- workspace layout (in floats) ----
#define WS_SEMB   0         // 12 floats
#define WS_GTOT   12        // 1 int global allocation cursor
#define WS_CNT    16        // NBINS ints
#define WS_OFFS   40016     // NBINS ints (int4/atom: run starts t=0,1,2 + end)
#define WS_CURSOR 80016     // NBINS ints
#define WS_EIDX   120016    // NEDGES ints: edge id, (atom,species)-sorted
#define WS_SA     440096    // NEDGES*32 floats: R[0..23] (+pad), 128B recs
#define WS_SB     10680096  // NEDGES*32 floats: R[24..47], rhat (+pad)

// multinomial term tables (global component index 0..34)
__device__ __constant__ int   d_PWA[35] = {0, 0,0,1, 0,0,0,1,1,2, 0,0,0,0,1,1,1,2,2,3, 0,0,0,0,0,1,1,1,1,2,2,2,3,3,4};
__device__ __constant__ int   d_PWB[35] = {0, 0,1,0, 0,1,2,0,1,0, 0,1,2,3,0,1,2,0,1,0, 0,1,2,3,4,0,1,2,3,0,1,2,0,1,0};
__device__ __constant__ int   d_PWC[35] = {0, 1,0,0, 2,1,0,1,0,0, 3,2,1,0,2,1,0,1,0,0, 4,3,2,1,0,3,2,1,0,2,1,0,1,0,0};
__device__ __constant__ float d_NM[35]  = {1.f, 1.f,1.f,1.f, 1.f,2.f,1.f,2.f,2.f,1.f,
                                           1.f,3.f,3.f,1.f,3.f,6.f,3.f,3.f,3.f,1.f,
                                           1.f,4.f,6.f,4.f,1.f,4.f,12.f,12.f,4.f,6.f,12.f,6.f,4.f,4.f,1.f};
__device__ __constant__ int   d_LBLK[35]= {0, 1,1,1, 2,2,2,2,2,2, 3,3,3,3,3,3,3,3,3,3, 4,4,4,4,4,4,4,4,4,4,4,4,4,4,4};
__device__ __constant__ int   d_L6[6]   = {0,1,4,10,20,35};

__device__ __forceinline__ float siluf(float x) { return x / (1.0f + __expf(-x)); }

__device__ __forceinline__ float2 f2fma(float2 a, float2 b, float2 c) {
  return make_float2(fmaf(a.x, b.x, c.x), fmaf(a.y, b.y, c.y));
}

__device__ __forceinline__ float psel(float x, int p) {
  float x2 = x * x;
  float r = 1.0f;
  r = (p == 1) ? x : r;
  r = (p == 2) ? x2 : r;
  r = (p == 3) ? x2 * x : r;
  r = (p == 4) ? x2 * x2 : r;
  return r;
}

// ---------------- k_init ----------------
__global__ void k_init(const float* __restrict__ Ws1, const float* __restrict__ bs1,
                       const float* __restrict__ Ws2, const float* __restrict__ bs2,
                       float* __restrict__ ws)
{
  int tid = blockIdx.x * blockDim.x + threadIdx.x;
  int* cnt = (int*)(ws + WS_CNT);
  if (tid < NBINS) cnt[tid] = 0;
  if (tid == 0) *(int*)(ws + WS_GTOT) = 0;
  if (tid < 12) {
    int t = tid >> 2, s = tid & 3;
    float acc = bs2[s];
    for (int j = 0; j < 16; j++) acc += tanhf(Ws1[t * 16 + j] + bs1[j]) * Ws2[j * 4 + s];
    ws[WS_SEMB + tid] = acc;
  }
}

// ---------------- k_hist: (atom,species)-bin counts ----------------
__global__ void k_hist(const int* __restrict__ first_atom, const int* __restrict__ second_atom,
                       const int* __restrict__ species, float* __restrict__ ws)
{
  int e = blockIdx.x * blockDim.x + threadIdx.x;
  if (e < NEDGES) {
    int* cnt = (int*)(ws + WS_CNT);
    int bin = first_atom[e] * 4 + species[second_atom[e]];
    atomicAdd(&cnt[bin], 1);
  }
}

// ---------------- k_alloc: decentralized run allocation, int4 per atom ----------------
__global__ __launch_bounds__(256) void k_alloc(float* __restrict__ ws)
{
  const int4* cnt4 = (const int4*)(ws + WS_CNT);
  int4* offs4   = (int4*)(ws + WS_OFFS);
  int4* cursor4 = (int4*)(ws + WS_CURSOR);
  int* gtot = (int*)(ws + WS_GTOT);
  __shared__ int wsum[4];
  __shared__ int sbase;
  int tid = threadIdx.x;
  int lane = tid & 63, wv = tid >> 6;
  int a = blockIdx.x * 256 + tid;
  bool live = (a < NATOMS);
  int4 c = live ? cnt4[a] : make_int4(0, 0, 0, 0);
  int s = c.x + c.y + c.z + c.w;
  int inc = s;
  #pragma unroll
  for (int d = 1; d < 64; d <<= 1) {
    int v = __shfl_up(inc, d, 64);
    if (lane >= d) inc += v;
  }
  if (lane == 63) wsum[wv] = inc;
  __syncthreads();
  if (tid == 0) sbase = atomicAdd(gtot, wsum[0] + wsum[1] + wsum[2] + wsum[3]);
  __syncthreads();
  int woff = sbase;
  for (int w = 0; w < wv; w++) woff += wsum[w];
  int o0 = woff + inc - s;
  if (live) {
    int4 o;
    o.x = o0;
    o.y = o.x + c.x;
    o.z = o.y + c.y;
    o.w = o.z + c.z;
    offs4[a] = o;
    cursor4[a] = o;
  }
}

// ---------------- k_edge: packed-FMA MLP -> half-record LDS rows -> 2 coalesced bursts ----------------
__global__ __launch_bounds__(256) void k_edge(
    const float* __restrict__ rij, const int* __restrict__ species,
    const int* __restrict__ first_atom, const int* __restrict__ second_atom,
    const float* __restrict__ Wr1, const float* __restrict__ br1,
    const float* __restrict__ Wr2, const float* __restrict__ br2,
    float* __restrict__ ws)
{
  __shared__ __align__(16) float sRec[4][64 * 28];
  int tid = threadIdx.x, lane = tid & 63, wv = tid >> 6;
  int e = blockIdx.x * 256 + tid;
  int* cursor = (int*)(ws + WS_CURSOR);
  int* eidx   = (int*)(ws + WS_EIDX);
  float* myrow = &sRec[wv][lane * 28];

  int a = first_atom[e];
  int t = species[second_atom[e]];
  int pos = atomicAdd(&cursor[a * 4 + t], 1);
  eidx[pos] = e;

  float x = rij[e * 3 + 0], y = rij[e * 3 + 1], z = rij[e * 3 + 2];
  float d = sqrtf(x * x + y * y + z * z + 1e-12f);
  float invd = 1.0f / d;

  float theta = (PI_F / RC_F) * d;
  float s1 = __sinf(theta), c1 = __cosf(theta);
  float fc = (d < RC_F) ? 0.5f * (c1 + 1.0f) : 0.0f;
  float bes[8];
  {
    float sq = sqrtf(2.0f / RC_F) * invd;
    float twoc = 2.0f * c1;
    float sp = 0.0f, sc = s1;
    #pragma unroll
    for (int k = 0; k < 8; k++) {
      bes[k] = sq * sc;
      float sn = twoc * sc - sp;
      sp = sc; sc = sn;
    }
  }

  float h1[64];
  #pragma unroll
  for (int j4 = 0; j4 < 16; j4++) {
    float2 a01 = *(const float2*)&br1[j4 * 4];
    float2 a23 = *(const float2*)&br1[j4 * 4 + 2];
    #pragma unroll
    for (int k = 0; k < 8; k++) {
      float2 b2 = make_float2(bes[k], bes[k]);
      a01 = f2fma(b2, *(const float2*)&Wr1[k * 64 + j4 * 4],     a01);
      a23 = f2fma(b2, *(const float2*)&Wr1[k * 64 + j4 * 4 + 2], a23);
    }
    h1[j4 * 4 + 0] = siluf(a01.x);
    h1[j4 * 4 + 1] = siluf(a01.y);
    h1[j4 * 4 + 2] = siluf(a23.x);
    h1[j4 * 4 + 3] = siluf(a23.y);
  }

  int ebase = blockIdx.x * 256 + wv * 64;
  const float* buf = &sRec[wv][0];
  int f4 = lane & 7;

  for (int j4 = 0; j4 < 6; j4++) {
    float2 a01 = *(const float2*)&br2[j4 * 4];
    float2 a23 = *(const float2*)&br2[j4 * 4 + 2];
    #pragma unroll
    for (int k = 0; k < 64; k++) {
      float2 h2 = make_float2(h1[k], h1[k]);
      a01 = f2fma(h2, *(const float2*)&Wr2[k * 48 + j4 * 4],     a01);
      a23 = f2fma(h2, *(const float2*)&Wr2[k * 48 + j4 * 4 + 2], a23);
    }
    *(float4*)(myrow + j4 * 4) = make_float4(siluf(a01.x) * fc, siluf(a01.y) * fc,
                                             siluf(a23.x) * fc, siluf(a23.y) * fc);
  }
  {
    float* gbase = ws + WS_SA + (size_t)ebase * 32;
    if (f4 < 6) {
      #pragma unroll
      for (int q = 0; q < 8; q++) {
        int g4 = q * 64 + lane;
        float4 v = *(const float4*)(buf + (g4 >> 3) * 28 + f4 * 4);
        *(float4*)(gbase + (size_t)g4 * 4) = v;
      }
    }
  }

  for (int j4 = 6; j4 < 12; j4++) {
    float2 a01 = *(const float2*)&br2[j4 * 4];
    float2 a23 = *(const float2*)&br2[j4 * 4 + 2];
    #pragma unroll
    for (int k = 0; k < 64; k++) {
      float2 h2 = make_float2(h1[k], h1[k]);
      a01 = f2fma(h2, *(const float2*)&Wr2[k * 48 + j4 * 4],     a01);
      a23 = f2fma(h2, *(const float2*)&Wr2[k * 48 + j4 * 4 + 2], a23);
    }
    *(float4*)(myrow + (j4 - 6) * 4) = make_float4(siluf(a01.x) * fc, siluf(a01.y) * fc,
                                                   siluf(a23.x) * fc, siluf(a23.y) * fc);
  }
  *(float4*)(myrow + 24) = make_float4(x * invd, y * invd, z * invd, 0.0f);
  {
    float* gbase = ws + WS_SB + (size_t)ebase * 32;
    if (f4 < 7) {
      #pragma unroll
      for (int q = 0; q < 8; q++) {
        int g4 = q * 64 + lane;
        float4 v = *(const float4*)(buf + (g4 >> 3) * 28 + f4 * 4);
        *(float4*)(gbase + (size_t)g4 * 4) = v;
      }
    }
  }
}

// ---------------- k_atom: 4 waves = 4 atoms; per-wave accumulation + COOPERATIVE epilogue ----------------
// Epilogue k-split: each wave streams 1/4 of Wa1/Wa2 and FMAs into all 4 atoms'
// partials (4x less weight traffic than per-wave epilogues, pipelinable loads).
__global__ __launch_bounds__(256) void k_atom(
    const float* __restrict__ ws,
    const float* __restrict__ Wa1, const float* __restrict__ ba1,
    const float* __restrict__ Wa2, const float* __restrict__ ba2,
    const float* __restrict__ Wa3, const float* __restrict__ ba3,
    float* __restrict__ out)
{
  __shared__ __align__(16) float sStage[4][768];   // triple-buffered gather stage per wave
  __shared__ __align__(16) float sG[4][864];       // G[t][r][36] per atom (col 35 = direct)
  __shared__ __align__(16) float sFeat[4][192];
  __shared__ __align__(16) float sP[4][4][64];     // [producer wave][atom][j]
  __shared__ __align__(16) float sH[4][64];
  __shared__ float sSemb[12];
  int tid = threadIdx.x;
  int lane = tid & 63, wv = tid >> 6;
  int a = blockIdx.x * 4 + wv;          // NATOMS = 2500*4 exact
  float* sStg = sStage[wv];
  float* sGw  = sG[wv];
  if (tid < 12) sSemb[tid] = ws[WS_SEMB + tid];

  const int* eidx = (const int*)(ws + WS_EIDX);
  int4 o = ((const int4*)(ws + WS_OFFS))[a];   // run starts t=0,1,2; o.w = end

  const int c = lane;
  bool isc = (c < 35);
  int pa = 0, pb = 0, pcw = 0, lb = 0;
  if (isc) { pa = d_PWA[c]; pb = d_PWB[c]; pcw = d_PWC[c]; lb = d_LBLK[c]; }
  int rdir = lane - 35;
  bool isd = (rdir >= 0) && (rdir < 8);
  int rl = lane >> 4, fl = lane & 15;
  const float* gsrc = ws + (fl < 6 ? WS_SA : WS_SB);
  int foff = (fl < 6) ? fl : ((fl < 13) ? fl - 6 : 6);

  float2 g2[3][4];
  #pragma unroll
  for (int t2 = 0; t2 < 3; t2++)
    #pragma unroll
    for (int r = 0; r < 4; r++) g2[t2][r] = make_float2(0.f, 0.f);
  float g0[3] = {0.0f, 0.0f, 0.0f};

#define CORE(T) {                                                             \
    const float* rb = buf + j * 64;                                           \
    if (isc) {                                                                \
      float comp = psel(rb[48], pa) * psel(rb[49], pb) * psel(rb[50], pcw);   \
      float2 c2 = make_float2(comp, comp);                                    \
      const float2* r2 = (const float2*)(rb + 8 + 8 * lb);                    \
      g2[T][0] = f2fma(c2, r2[0], g2[T][0]);                                  \
      g2[T][1] = f2fma(c2, r2[1], g2[T][1]);                                  \
      g2[T][2] = f2fma(c2, r2[2], g2[T][2]);                                  \
      g2[T][3] = f2fma(c2, r2[3], g2[T][3]);                                  \
    } else if (isd) {                                                         \
      g0[T] += rb[rdir];                                                      \
    }                                                                         \
  }

#define LOADR(Q, DST) {                                                       \
    int sl_ = (Q) * 4 + rl; if (sl_ >= m) sl_ = m - 1;                        \
    int pk_ = __shfl(packed, sl_, 64);                                        \
    DST = *(const float4*)(gsrc + (size_t)pk_ * 32 + foff * 4);               \
  }

#define RUN(T, LO, HI)                                                        \
  for (int cb = (LO); cb < (HI); cb += 64) {                                  \
    int m = (HI) - cb; if (m > 64) m = 64;                                    \
    int pp = cb + lane;                                                       \
    int packed = eidx[pp < (HI) ? pp : (LO)];                                 \
    int R = (m + 3) >> 2;                                                     \
    float4 v0, v1;                                                            \
    LOADR(0, v0)                                                              \
    if (R > 1) { LOADR(1, v1) } else v1 = v0;                                 \
    int bsel = 0;                                                             \
    for (int r = 0; r < R; r++) {                                             \
      float* buf = sStg + (bsel << 8);                                        \
      bsel = (bsel == 2) ? 0 : bsel + 1;                                      \
      *(float4*)(buf + rl * 64 + fl * 4) = v0;                                \
      v0 = v1;                                                                \
      if (r + 2 < R) LOADR(r + 2, v1)                                         \
      int g = r * 4, gm = m - g; if (gm > 4) gm = 4;                          \
      for (int j = 0; j < gm; j++) CORE(T)                                    \
    }                                                                         \
  }

  RUN(0, o.x, o.y)
  RUN(1, o.y, o.z)
  RUN(2, o.z, o.w)
#undef RUN
#undef CORE
#undef LOADR

  // write this wave's G (same-wave region)
  if (isc) {
    #pragma unroll
    for (int t2 = 0; t2 < 3; t2++)
      #pragma unroll
      for (int r = 0; r < 8; r++) {
        float gval = (r & 1) ? g2[t2][r >> 1].y : g2[t2][r >> 1].x;
        sGw[(t2 * 8 + r) * 36 + c] = gval;
      }
  } else if (isd) {
    #pragma unroll
    for (int t2 = 0; t2 < 3; t2++) sGw[(t2 * 8 + rdir) * 36 + 35] = g0[t2];
  }
  __syncthreads();

  // contraction: 768 feats over 256 threads (3 each); f=(blk*8+rr)*4+s
  #pragma unroll
  for (int u = 0; u < 3; u++) {
    int idx = tid + 256 * u;            // 0..767
    int i = idx / 192;
    int f = idx - i * 192;
    int s = f & 3, rr = (f >> 2) & 7, blk = f >> 5;
    float se0 = sSemb[s], se1 = sSemb[4 + s], se2 = sSemb[8 + s];
    const float* Gi = sG[i];
    float acc;
    if (blk == 0) {
      acc = se0 * Gi[(0 + rr) * 36 + 35] + se1 * Gi[(8 + rr) * 36 + 35] + se2 * Gi[(16 + rr) * 36 + 35];
    } else {
      int c0 = d_L6[blk - 1], c1 = d_L6[blk];
      acc = 0.0f;
      for (int cc = c0; cc < c1; cc++) {
        float A = se0 * Gi[(0 + rr) * 36 + cc] + se1 * Gi[(8 + rr) * 36 + cc] + se2 * Gi[(16 + rr) * 36 + cc];
        acc += d_NM[cc] * A * A;
      }
    }
    sFeat[i][f] = acc;
  }
  __syncthreads();

  // MLP layer 1: 192 -> 64; wave wv streams k in [wv*48, wv*48+48) for ALL 4 atoms
  {
    float a0 = 0.f, a1 = 0.f, a2 = 0.f, a3 = 0.f;
    int k0 = wv * 48;
    for (int kk = 0; kk < 48; kk += 4) {
      float4 f0 = *(const float4*)&sFeat[0][k0 + kk];
      float4 f1 = *(const float4*)&sFeat[1][k0 + kk];
      float4 f2 = *(const float4*)&sFeat[2][k0 + kk];
      float4 f3 = *(const float4*)&sFeat[3][k0 + kk];
      #pragma unroll
      for (int q = 0; q < 4; q++) {
        float w = Wa1[(k0 + kk + q) * 64 + lane];
        float e0 = (q == 0) ? f0.x : (q == 1) ? f0.y : (q == 2) ? f0.z : f0.w;
        float e1 = (q == 0) ? f1.x : (q == 1) ? f1.y : (q == 2) ? f1.z : f1.w;
        float e2 = (q == 0) ? f2.x : (q == 1) ? f2.y : (q == 2) ? f2.z : f2.w;
        float e3 = (q == 0) ? f3.x : (q == 1) ? f3.y : (q == 2) ? f3.z : f3.w;
        a0 = fmaf(e0, w, a0); a1 = fmaf(e1, w, a1);
        a2 = fmaf(e2, w, a2); a3 = fmaf(e3, w, a3);
      }
    }
    sP[wv][0][lane] = a0; sP[wv][1][lane] = a1;
    sP[wv][2][lane] = a2; sP[wv][3][lane] = a3;
  }
  __syncthreads();
  // reduce: thread (wv, lane) owns atom wv output j=lane
  sH[wv][lane] = siluf(sP[0][wv][lane] + sP[1][wv][lane] + sP[2][wv][lane] + sP[3][wv][lane] + ba1[lane]);
  __syncthreads();

  // MLP layer 2: 64 -> 64; wave wv streams k in [wv*16, wv*16+16)
  {
    float a0 = 0.f, a1 = 0.f, a2 = 0.f, a3 = 0.f;
    int k0 = wv * 16;
    for (int kk = 0; kk < 16; kk += 4) {
      float4 h0 = *(const float4*)&sH[0][k0 + kk];
      float4 h1v = *(const float4*)&sH[1][k0 + kk];
      float4 h2v = *(const float4*)&sH[2][k0 + kk];
      float4 h3 = *(const float4*)&sH[3][k0 + kk];
      #pragma unroll
      for (int q = 0; q < 4; q++) {
        float w = Wa2[(k0 + kk + q) * 64 + lane];
        float e0 = (q == 0) ? h0.x : (q == 1) ? h0.y : (q == 2) ? h0.z : h0.w;
        float e1 = (q == 0) ? h1v.x : (q == 1) ? h1v.y : (q == 2) ? h1v.z : h1v.w;
        float e2 = (q == 0) ? h2v.x : (q == 1) ? h2v.y : (q == 2) ? h2v.z : h2v.w;
        float e3 = (q == 0) ? h3.x : (q == 1) ? h3.y : (q == 2) ? h3.z : h3.w;
        a0 = fmaf(e0, w, a0); a1 = fmaf(e1, w, a1);
        a2 = fmaf(e2, w, a2); a3 = fmaf(e3, w, a3);
      }
    }
    sP[wv][0][lane] = a0; sP[wv][1][lane] = a1;
    sP[wv][2][lane] = a2; sP[wv][3][lane] = a3;
  }
  __syncthreads();
  // h2 + Wa3 product (thread (wv,lane) owns atom wv, j=lane); sH reused AFTER barrier
  {
    float h2 = siluf(sP[0][wv][lane] + sP[1][wv][lane] + sP[2][wv][lane] + sP[3][wv][lane] + ba2[lane]);
    float v = h2 * Wa3[lane];
    __syncthreads();                    // everyone done reading sH from layer 2
    sH[wv][lane] = v;
  }
  __syncthreads();
  // final: wave wv reduces its own atom
  {
    float pr = sH[wv][lane];
    #pragma unroll
    for (int off = 32; off > 0; off >>= 1) pr += __shfl_down(pr, off, 64);
    if (lane == 0) out[a] = pr + ba3[0];
  }
}

extern "C" void kernel_launch(void* const* d_in, const int* in_sizes, int n_in,
                              void* d_out, int out_size, void* d_ws, size_t ws_size,
                              hipStream_t stream)
{
  const float* rij         = (const float*)d_in[0];
  const int*   species     = (const int*)  d_in[1];
  const int*   first_atom  = (const int*)  d_in[2];
  const int*   second_atom = (const int*)  d_in[3];
  const float* Wr1 = (const float*)d_in[4];
  const float* br1 = (const float*)d_in[5];
  const float* Wr2 = (const float*)d_in[6];
  const float* br2 = (const float*)d_in[7];
  const float* Ws1 = (const float*)d_in[8];
  const float* bs1 = (const float*)d_in[9];
  const float* Ws2 = (const float*)d_in[10];
  const float* bs2 = (const float*)d_in[11];
  const float* Wa1 = (const float*)d_in[12];
  const float* ba1 = (const float*)d_in[13];
  const float* Wa2 = (const float*)d_in[14];
  const float* ba2 = (const float*)d_in[15];
  const float* Wa3 = (const float*)d_in[16];
  const float* ba3 = (const float*)d_in[17];
  float* ws  = (float*)d_ws;
  float* out = (float*)d_out;

  k_init<<<(NBINS + 255) / 256, 256, 0, stream>>>(Ws1, bs1, Ws2, bs2, ws);
  k_hist<<<(NEDGES + 255) / 256, 256, 0, stream>>>(first_atom, second_atom, species, ws);
  k_alloc<<<(NATOMS + 255) / 256, 256, 0, stream>>>(ws);
  k_edge<<<NEDGES / 256, 256, 0, stream>>>(rij, species, first_atom, second_atom,
                                           Wr1, br1, Wr2, br2, ws);
  k_atom<<<NATOMS / 4, 256, 0, stream>>>(ws, Wa1, ba1, Wa2, ba2, Wa3, ba3, out);
}